// Round 18
// baseline (215.035 us; speedup 1.0000x reference)
//
#include <hip/hip_runtime.h>
#include <cstdint>

typedef __attribute__((ext_vector_type(8))) short short8;
typedef __attribute__((ext_vector_type(8))) unsigned short ushort8;
typedef __attribute__((ext_vector_type(4))) unsigned short ushort4v;
typedef __attribute__((ext_vector_type(4))) float f32x4;

constexpr int NB = 256, MC = 128, MP = 256;
constexpr float L2E = 1.442695041f;

__device__ __forceinline__ float b2f(unsigned short h) { return __uint_as_float(((unsigned)h) << 16); }
__device__ __forceinline__ unsigned short f2b(float f) {
    unsigned u = __float_as_uint(f);
    u += 0x7fffu + ((u >> 16) & 1u);
    return (unsigned short)(u >> 16);
}
__device__ __forceinline__ float sigmoid_f(float x) {
    return __builtin_amdgcn_rcpf(1.f + exp2f(-L2E * x));
}
__device__ __forceinline__ void gld_lds16(const unsigned short* g, unsigned short* l) {
    __builtin_amdgcn_global_load_lds((const __attribute__((address_space(1))) void*)g,
                                     (__attribute__((address_space(3))) void*)l, 16, 0, 0);
}

__global__ __launch_bounds__(256)
void cvt_f32_bf16(const float* __restrict__ in, unsigned short* __restrict__ out, int n4) {
    int i = blockIdx.x * 256 + threadIdx.x;
    int stride = gridDim.x * 256;
    for (; i < n4; i += stride) {
        float4 v = ((const float4*)in)[i];
        ushort4v o;
        o.x = f2b(v.x); o.y = f2b(v.y); o.z = f2b(v.z); o.w = f2b(v.w);
        ((ushort4v*)out)[i] = o;
    }
}

// 8 weights -> Wcat [2048][256] bf16 + bias_cat[2048] f32.
// Row-block order: q_c,k_c,v_c,g_c,q_p,k_p,v_p,g_p (qkv contiguous per side).
__global__ __launch_bounds__(256)
void cvt_weights8(const float* w0, const float* w1, const float* w2, const float* w3,
                  const float* w4, const float* w5, const float* w6, const float* w7,
                  const float* b0, const float* b1, const float* b2, const float* b3,
                  const float* b4, const float* b5, const float* b6, const float* b7,
                  unsigned short* __restrict__ Wcat, float* __restrict__ bias_cat)
{
    const float* wsel[8] = {w0, w1, w2, w3, w4, w5, w6, w7};
    const float* bsel[8] = {b0, b1, b2, b3, b4, b5, b6, b7};
    int j = blockIdx.y;
    int i = blockIdx.x * 256 + threadIdx.x;
    float4 v = ((const float4*)wsel[j])[i];
    ushort4v o;
    o.x = f2b(v.x); o.y = f2b(v.y); o.z = f2b(v.z); o.w = f2b(v.w);
    ((ushort4v*)(Wcat + (size_t)j * 65536))[i] = o;
    if (blockIdx.x == 0) bias_cat[j * 256 + threadIdx.x] = bsel[j][threadIdx.x];
}

// ---------------------------------------------------------------------------
// Merged QKV projection (both entity sides in ONE dispatch), bf16 source.
// ---------------------------------------------------------------------------
__global__ __launch_bounds__(256, 4)
void proj_qkv(const unsigned short* __restrict__ comp_bf, const unsigned short* __restrict__ prot_bf,
              const unsigned short* __restrict__ Wcat, const float* __restrict__ bias_cat,
              unsigned short* __restrict__ tabC, unsigned short* __restrict__ tabP,
              int N_C, int N_P, int gpc)
{
    __shared__ __align__(16) unsigned short As[2][128 * 32];
    __shared__ __align__(16) unsigned short Bs[2][128 * 32];

    const bool isP = (int)blockIdx.x >= gpc;
    const unsigned short* A = isP ? prot_bf : comp_bf;
    unsigned short* C = isP ? tabP : tabC;
    const unsigned short* W = Wcat + (isP ? (size_t)1024 * 256 : 0);
    const float* bias = bias_cat + (isP ? 1024 : 0);
    const int M = isP ? N_P : N_C;
    const int bx = isP ? (int)blockIdx.x - gpc : (int)blockIdx.x;

    const int t = threadIdx.x;
    const int wid = t >> 6, l = t & 63, g = l >> 4, lr = l & 15;
    const int wrb = (wid >> 1) * 64, wcb = (wid & 1) * 64;
    const int r0 = bx * 128, c0 = blockIdx.y * 128;

    f32x4 acc[4][4];
#pragma unroll
    for (int mi = 0; mi < 4; ++mi)
#pragma unroll
        for (int ni = 0; ni < 4; ++ni) acc[mi][ni] = (f32x4){0.f, 0.f, 0.f, 0.f};

    auto stage = [&](int buf, int k0) {
#pragma unroll
        for (int p = 0; p < 2; ++p) {
            int i = p * 256 + t;
            int r = i >> 2, s = i & 3;
            int gr = r0 + r; if (gr >= M) gr = M - 1;
            gld_lds16(A + (size_t)gr * 256 + k0 + ((s ^ (r & 3)) << 3), &As[buf][i * 8]);
        }
#pragma unroll
        for (int p = 0; p < 2; ++p) {
            int i = p * 256 + t;
            int c = i >> 2, s = i & 3;
            gld_lds16(W + (size_t)(c0 + c) * 256 + k0 + ((s ^ (c & 3)) << 3), &Bs[buf][i * 8]);
        }
    };

    stage(0, 0);
    __syncthreads();
#pragma unroll
    for (int it = 0; it < 8; ++it) {
        const int cur = it & 1;
        if (it + 1 < 8) stage(cur ^ 1, (it + 1) << 5);
        short8 af[4], bfr[4];
#pragma unroll
        for (int mi = 0; mi < 4; ++mi) {
            int r = wrb + mi * 16 + lr;
            af[mi] = *(const short8*)&As[cur][r * 32 + ((g ^ (r & 3)) << 3)];
        }
#pragma unroll
        for (int ni = 0; ni < 4; ++ni) {
            int c = wcb + ni * 16 + lr;
            bfr[ni] = *(const short8*)&Bs[cur][c * 32 + ((g ^ (c & 3)) << 3)];
        }
#pragma unroll
        for (int mi = 0; mi < 4; ++mi)
#pragma unroll
            for (int ni = 0; ni < 4; ++ni)
                acc[mi][ni] = __builtin_amdgcn_mfma_f32_16x16x32_bf16(af[mi], bfr[ni], acc[mi][ni], 0, 0, 0);
        if (it + 1 < 8) __syncthreads();
    }

#pragma unroll
    for (int mi = 0; mi < 4; ++mi)
#pragma unroll
        for (int ni = 0; ni < 4; ++ni)
#pragma unroll
            for (int q = 0; q < 4; ++q) {
                int gr = r0 + wrb + mi * 16 + g * 4 + q;
                int gc = c0 + wcb + ni * 16 + lr;
                if (gr < M) C[(size_t)gr * 768 + gc] = f2b(acc[mi][ni][q] + bias[gc]);
            }
}

// ---------------------------------------------------------------------------
// Merged sigmoid gating with ragged ROW SKIP.
// ---------------------------------------------------------------------------
__global__ __launch_bounds__(256, 4)
void gate_both(unsigned short* __restrict__ F, const unsigned short* __restrict__ Wcat,
               const float* __restrict__ bias_cat,
               const int* __restrict__ clens, const int* __restrict__ plens)
{
    const int r0 = blockIdx.x * 64;
    const bool isP = r0 >= NB * MC;
    int bz, local;
    if (isP) { int rr = r0 - NB * MC; bz = rr >> 8; local = rr & 255; }
    else     { bz = r0 >> 7; local = r0 & 127; }
    const int len = isP ? plens[bz] : clens[bz];
    if (local >= len) return;   // all 64 rows masked -> outputs never read

    __shared__ __align__(16) unsigned short As[2][64 * 32];
    __shared__ __align__(16) unsigned short Bs[2][256 * 32];

    const int t = threadIdx.x;
    const int wid = t >> 6, l = t & 63, g = l >> 4, lr = l & 15;
    const unsigned short* W = Wcat + (size_t)(isP ? 1792 : 768) * 256;
    const float* bias = bias_cat + (isP ? 1792 : 768);
    const int wcb = wid * 64;

    f32x4 acc[4][4];
#pragma unroll
    for (int mi = 0; mi < 4; ++mi)
#pragma unroll
        for (int ni = 0; ni < 4; ++ni) acc[mi][ni] = (f32x4){0.f, 0.f, 0.f, 0.f};

    auto stage = [&](int buf, int k0) {
        {
            int i = t;
            int r = i >> 2, s = i & 3;
            gld_lds16(F + (size_t)(r0 + r) * 256 + k0 + ((s ^ (r & 3)) << 3), &As[buf][i * 8]);
        }
#pragma unroll
        for (int p = 0; p < 4; ++p) {
            int i = p * 256 + t;
            int c = i >> 2, s = i & 3;
            gld_lds16(W + (size_t)c * 256 + k0 + ((s ^ (c & 3)) << 3), &Bs[buf][i * 8]);
        }
    };

    stage(0, 0);
    __syncthreads();
#pragma unroll
    for (int it = 0; it < 8; ++it) {
        const int cur = it & 1;
        if (it + 1 < 8) stage(cur ^ 1, (it + 1) << 5);
        short8 af[4], bfr[4];
#pragma unroll
        for (int mi = 0; mi < 4; ++mi) {
            int r = mi * 16 + lr;
            af[mi] = *(const short8*)&As[cur][r * 32 + ((g ^ (r & 3)) << 3)];
        }
#pragma unroll
        for (int ni = 0; ni < 4; ++ni) {
            int c = wcb + ni * 16 + lr;
            bfr[ni] = *(const short8*)&Bs[cur][c * 32 + ((g ^ (c & 3)) << 3)];
        }
#pragma unroll
        for (int mi = 0; mi < 4; ++mi)
#pragma unroll
            for (int ni = 0; ni < 4; ++ni)
                acc[mi][ni] = __builtin_amdgcn_mfma_f32_16x16x32_bf16(af[mi], bfr[ni], acc[mi][ni], 0, 0, 0);
        if (it + 1 < 8) __syncthreads();
    }

#pragma unroll
    for (int mi = 0; mi < 4; ++mi)
#pragma unroll
        for (int ni = 0; ni < 4; ++ni)
#pragma unroll
            for (int q = 0; q < 4; ++q) {
                int gr = r0 + mi * 16 + g * 4 + q;
                int gc = wcb + ni * 16 + lr;
                size_t o = (size_t)gr * 256 + gc;
                F[o] = f2b(b2f(F[o]) * sigmoid_f(acc[mi][ni][q] + bias[gc]));
            }
}

// ---------------------------------------------------------------------------
// Mega-fused attention (R17 structure) + OCCUPANCY: Ps shrunk to [32][128]
// (PV over kcol processed in two halves for NN=256) -> LDS 34.3 -> 25.9 KB
// -> 6 blocks/CU. cp batches with cl<=128 skip the whole second half.
// Everything else identical to R17 (ragged skips, interleaved tile mapping).
// ---------------------------------------------------------------------------
struct AttnShared {
    unsigned short BVs[8192];       // K tiles; V reuses the region in PV
    unsigned short Ps[32 * 128];    // one kcol-half of P
    float red0[32][5];
    float red1[32][5];
};

template<int NN, int NRB, bool IMP>
__device__ __forceinline__
void attn_body(const unsigned short* __restrict__ Qt, const unsigned short* __restrict__ Kt,
               const unsigned short* __restrict__ Vt, unsigned short* __restrict__ O,
               const int* __restrict__ aidx, const int* __restrict__ bidx,
               const int* __restrict__ rlen, const int* __restrict__ cln,
               float* __restrict__ imp_c, float* __restrict__ imp_p_part,
               AttnShared& sh, int lid)
{
    constexpr int MB = 32;
    constexpr int QI = 2;
    constexpr int KI = NN / 64;
    constexpr int NCH = NN / 32;
    constexpr int Mfull = MB * NRB;

    const int t = threadIdx.x;
    const int wid = t >> 6, l = t & 63, g = l >> 4, lr = l & 15;
    const int xcd = lid & 7;
    const int j = lid >> 3;
    const int rowblk = j % NRB;
    const int bz = (j / NRB) * 8 + xcd;
    const int rbase = rowblk * MB;
    const int rl = rlen[bz], cl_ = cln[bz];

    if (rbase >= rl) return;   // whole row-block masked: outputs never read

    // interleaved tile -> kcol mapping
    int kbase[KI];
    bool kneed[KI];
#pragma unroll
    for (int p = 0; p < KI; ++p) {
        kbase[p] = (p * 4 + wid) * 16;
        kneed[p] = kbase[p] < cl_;
    }

    const unsigned short* kp[KI];
#pragma unroll
    for (int p = 0; p < KI; ++p) {
        int c = kbase[p] + (l >> 2);
        kp[p] = Kt + (size_t)bidx[bz * NN + c] * 768 + (((l & 3) ^ (c & 3)) << 3);
    }
    const unsigned short* qp[QI];
#pragma unroll
    for (int qi = 0; qi < QI; ++qi)
        qp[qi] = Qt + (size_t)aidx[bz * Mfull + rbase + qi * 16 + lr] * 768 + g * 8;

    auto stageK = [&](int k0) {
#pragma unroll
        for (int p = 0; p < KI; ++p)
            if (kneed[p])
                gld_lds16(kp[p] + k0, &sh.BVs[kbase[p] * 32 + l * 8]);
    };

    f32x4 acc[KI][QI];
#pragma unroll
    for (int ki = 0; ki < KI; ++ki)
#pragma unroll
        for (int qi = 0; qi < QI; ++qi) acc[ki][qi] = (f32x4){0.f, 0.f, 0.f, 0.f};

    short8 afb[2][QI];
    stageK(0);
#pragma unroll
    for (int qi = 0; qi < QI; ++qi) afb[0][qi] = *(const short8*)(qp[qi]);

    // ---- QK loop: single-buffered, self-paced (TLP hides latency) ----
#pragma unroll
    for (int it = 0; it < 8; ++it) {
        const int cur = it & 1;
        asm volatile("s_waitcnt vmcnt(0)" ::: "memory");
        __builtin_amdgcn_sched_barrier(0);
        short8 bf[KI];
#pragma unroll
        for (int ki = 0; ki < KI; ++ki)
            if (kneed[ki]) {
                int c = kbase[ki] + lr;
                bf[ki] = *(const short8*)&sh.BVs[c * 32 + ((g ^ (c & 3)) << 3)];
            }
        if (it < 7) {
            asm volatile("s_waitcnt lgkmcnt(0)" ::: "memory");
            __builtin_amdgcn_sched_barrier(0);
            stageK((it + 1) * 32);
#pragma unroll
            for (int qi = 0; qi < QI; ++qi)
                afb[cur ^ 1][qi] = *(const short8*)(qp[qi] + (it + 1) * 32);
        }
#pragma unroll
        for (int ki = 0; ki < KI; ++ki)
            if (kneed[ki])
#pragma unroll
                for (int qi = 0; qi < QI; ++qi)
                    acc[ki][qi] = __builtin_amdgcn_mfma_f32_16x16x32_bf16(bf[ki], afb[cur][qi], acc[ki][qi], 0, 0, 0);
    }

    // ---- issue V chunk-0 gathers (fly under softmax); wave-private dims ----
    const int va = l & 15, vcb = wid * 64 + (l >> 4) * 16;
    ushort8 v0a, v0b, v1a, v1b;
    {
        const unsigned short* q0 = Vt + (size_t)bidx[bz * NN + 2 * va] * 768 + vcb;
        const unsigned short* q1 = Vt + (size_t)bidx[bz * NN + 2 * va + 1] * 768 + vcb;
        v0a = *(const ushort8*)q0; v0b = *(const ushort8*)(q0 + 8);
        v1a = *(const ushort8*)q1; v1b = *(const ushort8*)(q1 + 8);
    }
    auto writeV = [&]() {
        int gg = va >> 2, kl = (2 * va) & 7;
#pragma unroll
        for (int e = 0; e < 8; ++e) {
            int c = vcb + e;
            *(unsigned*)&sh.BVs[c * 32 + ((gg ^ (c & 3)) << 3) + kl] =
                (unsigned)(unsigned short)v0a[e] | ((unsigned)(unsigned short)v1a[e] << 16);
        }
#pragma unroll
        for (int e = 0; e < 8; ++e) {
            int c = vcb + 8 + e;
            *(unsigned*)&sh.BVs[c * 32 + ((gg ^ (c & 3)) << 3) + kl] =
                (unsigned)(unsigned short)v0b[e] | ((unsigned)(unsigned short)v1b[e] << 16);
        }
    };

    // ---- mask + scale (covers skipped tiles: their acc==0 -> -1e9) ----
#pragma unroll
    for (int ki = 0; ki < KI; ++ki)
#pragma unroll
        for (int qi = 0; qi < QI; ++qi)
#pragma unroll
            for (int q = 0; q < 4; ++q) {
                int kcol = kbase[ki] + g * 4 + q;
                int qrow = rbase + qi * 16 + lr;
                acc[ki][qi][q] = (qrow < rl && kcol < cl_) ? acc[ki][qi][q] * 0.0625f : -1e9f;
            }

    // ---- row max ----
    float mx[QI], inv[QI];
#pragma unroll
    for (int qi = 0; qi < QI; ++qi) {
        float m = -1e30f;
#pragma unroll
        for (int ki = 0; ki < KI; ++ki)
#pragma unroll
            for (int q = 0; q < 4; ++q) m = fmaxf(m, acc[ki][qi][q]);
        m = fmaxf(m, __shfl_xor(m, 16));
        m = fmaxf(m, __shfl_xor(m, 32));
        mx[qi] = m;
    }
    if (g == 0)
#pragma unroll
        for (int qi = 0; qi < QI; ++qi) sh.red0[qi * 16 + lr][wid] = mx[qi];
    __syncthreads();   // B1 (all QK LDS reads complete block-wide)
#pragma unroll
    for (int qi = 0; qi < QI; ++qi) {
        int row = qi * 16 + lr;
        mx[qi] = fmaxf(fmaxf(sh.red0[row][0], sh.red0[row][1]), fmaxf(sh.red0[row][2], sh.red0[row][3]));
    }

    // ---- exp + row sum ----
#pragma unroll
    for (int qi = 0; qi < QI; ++qi) {
        float s = 0.f;
#pragma unroll
        for (int ki = 0; ki < KI; ++ki)
#pragma unroll
            for (int q = 0; q < 4; ++q) {
                float e = exp2f((acc[ki][qi][q] - mx[qi]) * L2E);
                acc[ki][qi][q] = e;
                s += e;
            }
        s += __shfl_xor(s, 16);
        s += __shfl_xor(s, 32);
        mx[qi] = s;
    }
    if (g == 0)
#pragma unroll
        for (int qi = 0; qi < QI; ++qi) sh.red1[qi * 16 + lr][wid] = mx[qi];
    writeV();          // V chunk 0 (post-B1, wave-private region)
    __syncthreads();   // B2
#pragma unroll
    for (int qi = 0; qi < QI; ++qi) {
        int row = qi * 16 + lr;
        inv[qi] = 1.f / (sh.red1[row][0] + sh.red1[row][1] + sh.red1[row][2] + sh.red1[row][3]);
    }

    if constexpr (IMP) {
        if (wid == 0 && g == 0)
#pragma unroll
            for (int qi = 0; qi < QI; ++qi)
                imp_c[bz * Mfull + rbase + qi * 16 + lr] = inv[qi];
#pragma unroll
        for (int ki = 0; ki < KI; ++ki)
#pragma unroll
            for (int q = 0; q < 4; ++q) {
                float m = -1e30f;
#pragma unroll
                for (int qi = 0; qi < QI; ++qi) {
                    bool vr = (rbase + qi * 16 + lr) < rl;
                    m = fmaxf(m, vr ? acc[ki][qi][q] * inv[qi] : -1e30f);
                }
#pragma unroll
                for (int o = 1; o < 16; o <<= 1) m = fmaxf(m, __shfl_xor(m, o));
                if (lr == 0) {
                    int kcol = kbase[ki] + g * 4 + q;
                    imp_p_part[((size_t)rowblk * NB + bz) * NN + kcol] = m;
                }
            }
    }

    // ---- PV over kcol halves: pack P-half -> barrier -> 4 chunks ----
    const int NCHv = ((cl_ + 31) >> 5) < NCH ? ((cl_ + 31) >> 5) : NCH;
    const int hpmax = (NCHv + 3) >> 2;   // 1 (pc, or cp with cl<=128) or 2
    constexpr int KH = (KI >= 2) ? KI / ((NN == 256) ? 2 : 1) : KI;  // tiles per half

    f32x4 acc2[4][QI];
#pragma unroll
    for (int di = 0; di < 4; ++di)
#pragma unroll
        for (int qi = 0; qi < QI; ++qi) acc2[di][qi] = (f32x4){0.f, 0.f, 0.f, 0.f};

    for (int hp = 0; hp < hpmax; ++hp) {
        // pack this half's P tiles (slots indexed by kcol within half)
#pragma unroll
        for (int kk = 0; kk < KH; ++kk) {
            int ki = hp * KH + kk;
#pragma unroll
            for (int qi = 0; qi < QI; ++qi) {
                int row = qi * 16 + lr;
                int slot = ((kbase[ki] >> 2) & 31) + g;
                int slotp = slot ^ ((lr & 7) << 1);
                ushort4v pk;
                pk.x = f2b(acc[ki][qi][0] * inv[qi]);
                pk.y = f2b(acc[ki][qi][1] * inv[qi]);
                pk.z = f2b(acc[ki][qi][2] * inv[qi]);
                pk.w = f2b(acc[ki][qi][3] * inv[qi]);
                *(ushort4v*)&sh.Ps[row * 128 + slotp * 4] = pk;
            }
        }
        __syncthreads();   // P half visible (hp=0: also Ps-handoff)

        const int chEnd = ((hp + 1) * 4 < NCHv) ? (hp + 1) * 4 : NCHv;
        for (int ch = hp * 4; ch < chEnd; ++ch) {
            if (ch + 1 < NCHv) {
                const unsigned short* q0 = Vt + (size_t)bidx[bz * NN + (ch + 1) * 32 + 2 * va] * 768 + vcb;
                const unsigned short* q1 = Vt + (size_t)bidx[bz * NN + (ch + 1) * 32 + 2 * va + 1] * 768 + vcb;
                v0a = *(const ushort8*)q0; v0b = *(const ushort8*)(q0 + 8);
                v1a = *(const ushort8*)q1; v1b = *(const ushort8*)(q1 + 8);
            }
            short8 pf[QI], vf[4];
            const int chl = ch & 3;
#pragma unroll
            for (int qi = 0; qi < QI; ++qi) {
                int row = qi * 16 + lr;
                int slotr = (chl * 8 + 2 * g) ^ ((lr & 7) << 1);
                pf[qi] = *(const short8*)&sh.Ps[row * 128 + slotr * 4];
            }
#pragma unroll
            for (int di = 0; di < 4; ++di) {
                int c = wid * 64 + di * 16 + lr;
                vf[di] = *(const short8*)&sh.BVs[c * 32 + ((g ^ (c & 3)) << 3)];
            }
#pragma unroll
            for (int di = 0; di < 4; ++di)
#pragma unroll
                for (int qi = 0; qi < QI; ++qi)
                    acc2[di][qi] = __builtin_amdgcn_mfma_f32_16x16x32_bf16(vf[di], pf[qi], acc2[di][qi], 0, 0, 0);
            if (ch + 1 < NCHv) {
                asm volatile("s_waitcnt lgkmcnt(0)" ::: "memory");
                __builtin_amdgcn_sched_barrier(0);
                writeV();
            }
        }
        if (hp + 1 < hpmax) __syncthreads();   // half's P reads done before repack
    }

    // ---- packed fused-output stores ----
#pragma unroll
    for (int di = 0; di < 4; ++di)
#pragma unroll
        for (int qi = 0; qi < QI; ++qi) {
            int qrow = qi * 16 + lr;
            int dim = wid * 64 + di * 16 + g * 4;
            ushort4v pk;
            pk.x = f2b(acc2[di][qi][0]);
            pk.y = f2b(acc2[di][qi][1]);
            pk.z = f2b(acc2[di][qi][2]);
            pk.w = f2b(acc2[di][qi][3]);
            *(ushort4v*)&O[((size_t)bz * Mfull + rbase + qrow) * 256 + dim] = pk;
        }
}

// Both attention directions in ONE dispatch, 6 blocks/CU.
__global__ __launch_bounds__(256, 6)
void attn_both(const unsigned short* __restrict__ tabC, const unsigned short* __restrict__ tabP,
               unsigned short* __restrict__ cfused, unsigned short* __restrict__ pfused,
               const int* __restrict__ comp_idx, const int* __restrict__ prot_idx,
               const int* __restrict__ comp_lens, const int* __restrict__ prot_lens,
               float* __restrict__ imp_c, float* __restrict__ imp_p_part)
{
    __shared__ AttnShared sh;
    const int lid = blockIdx.x;
    if (lid < 4 * NB)
        attn_body<256, 4, true>(tabC, tabP + 256, tabP + 512, cfused,
            comp_idx, prot_idx, comp_lens, prot_lens, imp_c, imp_p_part, sh, lid);
    else
        attn_body<128, 8, false>(tabP, tabC + 256, tabC + 512, pfused,
            prot_idx, comp_idx, prot_lens, comp_lens, nullptr, nullptr, sh, lid - 4 * NB);
}

__device__ __forceinline__ float br_max(float v, float* red)
{
#pragma unroll
    for (int o = 32; o; o >>= 1) v = fmaxf(v, __shfl_xor(v, o));
    __syncthreads();
    if ((threadIdx.x & 63) == 0) red[threadIdx.x >> 6] = v;
    __syncthreads();
    return fmaxf(fmaxf(red[0], red[1]), fmaxf(red[2], red[3]));
}

__device__ __forceinline__ float br_sum(float v, float* red)
{
#pragma unroll
    for (int o = 32; o; o >>= 1) v += __shfl_xor(v, o);
    __syncthreads();
    if ((threadIdx.x & 63) == 0) red[threadIdx.x >> 6] = v;
    __syncthreads();
    return red[0] + red[1] + red[2] + red[3];
}

__global__ __launch_bounds__(256)
void pool_kernel(const unsigned short* __restrict__ cg, const unsigned short* __restrict__ pg,
                 const float* __restrict__ imp_c, const float* __restrict__ imp_p_part,
                 const int* __restrict__ clens, const int* __restrict__ plens,
                 float* __restrict__ out)
{
    int b = blockIdx.x, t = threadIdx.x;
    __shared__ float w[256];
    __shared__ float red[4];
    int cl = clens[b], pl = plens[b];

    float x = (t < 128 && t < cl) ? imp_c[b * MC + t] : -1e30f;
    float mx = br_max(x, red);
    float e = (t < 128) ? exp2f((x - mx) * L2E) : 0.f;
    float s = br_sum(e, red);
    if (t < 128) w[t] = e / s;
    __syncthreads();

    float hv = 0.f;
    for (int n = 0; n < cl; ++n)
        hv += w[n] * b2f(cg[((size_t)b * MC + n) * 256 + t]);
    __syncthreads();

    const int nv = (cl + 31) >> 5;
    float x2 = -1e30f;
    if (t < pl) {
        x2 = imp_p_part[(size_t)b * MP + t];
        for (int jj = 1; jj < nv; ++jj)
            x2 = fmaxf(x2, imp_p_part[(size_t)(jj * NB + b) * MP + t]);
    }
    float mx2 = br_max(x2, red);
    float e2 = exp2f((x2 - mx2) * L2E);
    float s2 = br_sum(e2, red);
    w[t] = e2 / s2;
    __syncthreads();

    float dv = 0.f;
    for (int m = 0; m < pl; ++m)
        dv += w[m] * b2f(pg[((size_t)b * MP + m) * 256 + t]);

    float logit = br_sum(hv * dv, red);
    if (t == 0) out[b] = 1.f / (1.f + expf(-logit));
}

// ---------------------------------------------------------------------------
extern "C" void kernel_launch(void* const* d_in, const int* in_sizes, int n_in,
                              void* d_out, int out_size, void* d_ws, size_t ws_size,
                              hipStream_t stream)
{
    const float* comp_emb = (const float*)d_in[0];
    const float* prot_emb = (const float*)d_in[1];
    const int* comp_idx  = (const int*)d_in[18];
    const int* prot_idx  = (const int*)d_in[19];
    const int* comp_lens = (const int*)d_in[20];
    const int* prot_lens = (const int*)d_in[21];
    float* out = (float*)d_out;

    const int N_C = in_sizes[0] / 256;
    const int N_P = in_sizes[1] / 256;
    const size_t NTc = (size_t)N_C * 256;
    const size_t NTp = (size_t)N_P * 256;

    // ---- workspace layout (bf16 elems) ----
    unsigned short* comp_bf = (unsigned short*)d_ws;
    unsigned short* prot_bf = comp_bf + NTc;
    unsigned short* Wcat    = prot_bf + NTp;                 // [2048][256]
    float* bias_cat         = (float*)(Wcat + 2048 * 256);   // [2048]
    unsigned short* tabC    = (unsigned short*)(bias_cat + 2048);  // [N_C][768] q|k|v
    unsigned short* tabP    = tabC + (size_t)N_C * 768;            // [N_P][768] q|k|v
    unsigned short* cfused  = tabP + (size_t)N_P * 768;      // [NB][128][256]
    unsigned short* pfused  = cfused + (size_t)NB * MC * 256; // [NB][256][256] (contiguous)
    float* imp_c      = (float*)(pfused + (size_t)NB * MP * 256);
    float* imp_p_part = imp_c + NB * MC;                     // [4][NB][256]

    // ---- conversions ----
    cvt_f32_bf16<<<dim3(2048), 256, 0, stream>>>(comp_emb, comp_bf, (int)(NTc / 4));
    cvt_f32_bf16<<<dim3(2048), 256, 0, stream>>>(prot_emb, prot_bf, (int)(NTp / 4));
    cvt_weights8<<<dim3(64, 8), 256, 0, stream>>>(
        (const float*)d_in[2], (const float*)d_in[4], (const float*)d_in[6], (const float*)d_in[14],
        (const float*)d_in[8], (const float*)d_in[10], (const float*)d_in[12], (const float*)d_in[16],
        (const float*)d_in[3], (const float*)d_in[5], (const float*)d_in[7], (const float*)d_in[15],
        (const float*)d_in[9], (const float*)d_in[11], (const float*)d_in[13], (const float*)d_in[17],
        Wcat, bias_cat);

    const int gpc = (N_C + 127) / 128, gpp = (N_P + 127) / 128;

    // ---- merged qkv projection (both sides, one dispatch) ----
    proj_qkv<<<dim3(gpc + gpp, 6), 256, 0, stream>>>(comp_bf, prot_bf, Wcat, bias_cat,
        tabC, tabP, N_C, N_P, gpc);

    // ---- merged attention (ragged skips, 6 blocks/CU) ----
    attn_both<<<dim3(4 * NB + 8 * NB), 256, 0, stream>>>(
        tabC, tabP, cfused, pfused,
        comp_idx, prot_idx, comp_lens, prot_lens, imp_c, imp_p_part);

    // ---- merged sigmoid gating (both tensors, ragged row skip) ----
    gate_both<<<dim3((NB * MC + NB * MP) / 64), 256, 0, stream>>>(cfused, Wcat, bias_cat,
        comp_lens, prot_lens);

    // ---- pooling + logit (bounded loops) ----
    pool_kernel<<<dim3(NB), 256, 0, stream>>>(cfused, pfused, imp_c, imp_p_part, comp_lens, prot_lens, out);
}

// Round 19
// 183.345 us; speedup vs baseline: 1.1728x; 1.1728x over previous
//
#include <hip/hip_runtime.h>
#include <cstdint>

typedef __attribute__((ext_vector_type(8))) short short8;
typedef __attribute__((ext_vector_type(8))) unsigned short ushort8;
typedef __attribute__((ext_vector_type(4))) unsigned short ushort4v;
typedef __attribute__((ext_vector_type(4))) float f32x4;

constexpr int NB = 256, MC = 128, MP = 256;
constexpr float L2E = 1.442695041f;

__device__ __forceinline__ float b2f(unsigned short h) { return __uint_as_float(((unsigned)h) << 16); }
__device__ __forceinline__ unsigned short f2b(float f) {
    unsigned u = __float_as_uint(f);
    u += 0x7fffu + ((u >> 16) & 1u);
    return (unsigned short)(u >> 16);
}
__device__ __forceinline__ float sigmoid_f(float x) {
    return __builtin_amdgcn_rcpf(1.f + exp2f(-L2E * x));
}
__device__ __forceinline__ void gld_lds16(const unsigned short* g, unsigned short* l) {
    __builtin_amdgcn_global_load_lds((const __attribute__((address_space(1))) void*)g,
                                     (__attribute__((address_space(3))) void*)l, 16, 0, 0);
}

__global__ __launch_bounds__(256)
void cvt_f32_bf16(const float* __restrict__ in, unsigned short* __restrict__ out, int n4) {
    int i = blockIdx.x * 256 + threadIdx.x;
    int stride = gridDim.x * 256;
    for (; i < n4; i += stride) {
        float4 v = ((const float4*)in)[i];
        ushort4v o;
        o.x = f2b(v.x); o.y = f2b(v.y); o.z = f2b(v.z); o.w = f2b(v.w);
        ((ushort4v*)out)[i] = o;
    }
}

// 8 weights -> Wcat [2048][256] bf16 + bias_cat[2048] f32.
// Row-block order: q_c,k_c,v_c,g_c,q_p,k_p,v_p,g_p (qkv contiguous per side).
__global__ __launch_bounds__(256)
void cvt_weights8(const float* w0, const float* w1, const float* w2, const float* w3,
                  const float* w4, const float* w5, const float* w6, const float* w7,
                  const float* b0, const float* b1, const float* b2, const float* b3,
                  const float* b4, const float* b5, const float* b6, const float* b7,
                  unsigned short* __restrict__ Wcat, float* __restrict__ bias_cat)
{
    const float* wsel[8] = {w0, w1, w2, w3, w4, w5, w6, w7};
    const float* bsel[8] = {b0, b1, b2, b3, b4, b5, b6, b7};
    int j = blockIdx.y;
    int i = blockIdx.x * 256 + threadIdx.x;
    float4 v = ((const float4*)wsel[j])[i];
    ushort4v o;
    o.x = f2b(v.x); o.y = f2b(v.y); o.z = f2b(v.z); o.w = f2b(v.w);
    ((ushort4v*)(Wcat + (size_t)j * 65536))[i] = o;
    if (blockIdx.x == 0) bias_cat[j * 256 + threadIdx.x] = bsel[j][threadIdx.x];
}

// ---------------------------------------------------------------------------
// Merged QKV projection (both entity sides in ONE dispatch), bf16 source.
// ---------------------------------------------------------------------------
__global__ __launch_bounds__(256, 4)
void proj_qkv(const unsigned short* __restrict__ comp_bf, const unsigned short* __restrict__ prot_bf,
              const unsigned short* __restrict__ Wcat, const float* __restrict__ bias_cat,
              unsigned short* __restrict__ tabC, unsigned short* __restrict__ tabP,
              int N_C, int N_P, int gpc)
{
    __shared__ __align__(16) unsigned short As[2][128 * 32];
    __shared__ __align__(16) unsigned short Bs[2][128 * 32];

    const bool isP = (int)blockIdx.x >= gpc;
    const unsigned short* A = isP ? prot_bf : comp_bf;
    unsigned short* C = isP ? tabP : tabC;
    const unsigned short* W = Wcat + (isP ? (size_t)1024 * 256 : 0);
    const float* bias = bias_cat + (isP ? 1024 : 0);
    const int M = isP ? N_P : N_C;
    const int bx = isP ? (int)blockIdx.x - gpc : (int)blockIdx.x;

    const int t = threadIdx.x;
    const int wid = t >> 6, l = t & 63, g = l >> 4, lr = l & 15;
    const int wrb = (wid >> 1) * 64, wcb = (wid & 1) * 64;
    const int r0 = bx * 128, c0 = blockIdx.y * 128;

    f32x4 acc[4][4];
#pragma unroll
    for (int mi = 0; mi < 4; ++mi)
#pragma unroll
        for (int ni = 0; ni < 4; ++ni) acc[mi][ni] = (f32x4){0.f, 0.f, 0.f, 0.f};

    auto stage = [&](int buf, int k0) {
#pragma unroll
        for (int p = 0; p < 2; ++p) {
            int i = p * 256 + t;
            int r = i >> 2, s = i & 3;
            int gr = r0 + r; if (gr >= M) gr = M - 1;
            gld_lds16(A + (size_t)gr * 256 + k0 + ((s ^ (r & 3)) << 3), &As[buf][i * 8]);
        }
#pragma unroll
        for (int p = 0; p < 2; ++p) {
            int i = p * 256 + t;
            int c = i >> 2, s = i & 3;
            gld_lds16(W + (size_t)(c0 + c) * 256 + k0 + ((s ^ (c & 3)) << 3), &Bs[buf][i * 8]);
        }
    };

    stage(0, 0);
    __syncthreads();
#pragma unroll
    for (int it = 0; it < 8; ++it) {
        const int cur = it & 1;
        if (it + 1 < 8) stage(cur ^ 1, (it + 1) << 5);
        short8 af[4], bfr[4];
#pragma unroll
        for (int mi = 0; mi < 4; ++mi) {
            int r = wrb + mi * 16 + lr;
            af[mi] = *(const short8*)&As[cur][r * 32 + ((g ^ (r & 3)) << 3)];
        }
#pragma unroll
        for (int ni = 0; ni < 4; ++ni) {
            int c = wcb + ni * 16 + lr;
            bfr[ni] = *(const short8*)&Bs[cur][c * 32 + ((g ^ (c & 3)) << 3)];
        }
#pragma unroll
        for (int mi = 0; mi < 4; ++mi)
#pragma unroll
            for (int ni = 0; ni < 4; ++ni)
                acc[mi][ni] = __builtin_amdgcn_mfma_f32_16x16x32_bf16(af[mi], bfr[ni], acc[mi][ni], 0, 0, 0);
        if (it + 1 < 8) __syncthreads();
    }

#pragma unroll
    for (int mi = 0; mi < 4; ++mi)
#pragma unroll
        for (int ni = 0; ni < 4; ++ni)
#pragma unroll
            for (int q = 0; q < 4; ++q) {
                int gr = r0 + wrb + mi * 16 + g * 4 + q;
                int gc = c0 + wcb + ni * 16 + lr;
                if (gr < M) C[(size_t)gr * 768 + gc] = f2b(acc[mi][ni][q] + bias[gc]);
            }
}

// ---------------------------------------------------------------------------
// Merged sigmoid gating with ragged ROW SKIP.
// ---------------------------------------------------------------------------
__global__ __launch_bounds__(256, 4)
void gate_both(unsigned short* __restrict__ F, const unsigned short* __restrict__ Wcat,
               const float* __restrict__ bias_cat,
               const int* __restrict__ clens, const int* __restrict__ plens)
{
    const int r0 = blockIdx.x * 64;
    const bool isP = r0 >= NB * MC;
    int bz, local;
    if (isP) { int rr = r0 - NB * MC; bz = rr >> 8; local = rr & 255; }
    else     { bz = r0 >> 7; local = r0 & 127; }
    const int len = isP ? plens[bz] : clens[bz];
    if (local >= len) return;   // all 64 rows masked -> outputs never read

    __shared__ __align__(16) unsigned short As[2][64 * 32];
    __shared__ __align__(16) unsigned short Bs[2][256 * 32];

    const int t = threadIdx.x;
    const int wid = t >> 6, l = t & 63, g = l >> 4, lr = l & 15;
    const unsigned short* W = Wcat + (size_t)(isP ? 1792 : 768) * 256;
    const float* bias = bias_cat + (isP ? 1792 : 768);
    const int wcb = wid * 64;

    f32x4 acc[4][4];
#pragma unroll
    for (int mi = 0; mi < 4; ++mi)
#pragma unroll
        for (int ni = 0; ni < 4; ++ni) acc[mi][ni] = (f32x4){0.f, 0.f, 0.f, 0.f};

    auto stage = [&](int buf, int k0) {
        {
            int i = t;
            int r = i >> 2, s = i & 3;
            gld_lds16(F + (size_t)(r0 + r) * 256 + k0 + ((s ^ (r & 3)) << 3), &As[buf][i * 8]);
        }
#pragma unroll
        for (int p = 0; p < 4; ++p) {
            int i = p * 256 + t;
            int c = i >> 2, s = i & 3;
            gld_lds16(W + (size_t)c * 256 + k0 + ((s ^ (c & 3)) << 3), &Bs[buf][i * 8]);
        }
    };

    stage(0, 0);
    __syncthreads();
#pragma unroll
    for (int it = 0; it < 8; ++it) {
        const int cur = it & 1;
        if (it + 1 < 8) stage(cur ^ 1, (it + 1) << 5);
        short8 af[4], bfr[4];
#pragma unroll
        for (int mi = 0; mi < 4; ++mi) {
            int r = mi * 16 + lr;
            af[mi] = *(const short8*)&As[cur][r * 32 + ((g ^ (r & 3)) << 3)];
        }
#pragma unroll
        for (int ni = 0; ni < 4; ++ni) {
            int c = wcb + ni * 16 + lr;
            bfr[ni] = *(const short8*)&Bs[cur][c * 32 + ((g ^ (c & 3)) << 3)];
        }
#pragma unroll
        for (int mi = 0; mi < 4; ++mi)
#pragma unroll
            for (int ni = 0; ni < 4; ++ni)
                acc[mi][ni] = __builtin_amdgcn_mfma_f32_16x16x32_bf16(af[mi], bfr[ni], acc[mi][ni], 0, 0, 0);
        if (it + 1 < 8) __syncthreads();
    }

#pragma unroll
    for (int mi = 0; mi < 4; ++mi)
#pragma unroll
        for (int ni = 0; ni < 4; ++ni)
#pragma unroll
            for (int q = 0; q < 4; ++q) {
                int gr = r0 + mi * 16 + g * 4 + q;
                int gc = wcb + ni * 16 + lr;
                size_t o = (size_t)gr * 256 + gc;
                F[o] = f2b(b2f(F[o]) * sigmoid_f(acc[mi][ni][q] + bias[gc]));
            }
}

// ---------------------------------------------------------------------------
// Mega-fused attention: R18 structure with the rule-#20 fix — the PV half
// loop is UNROLLED AT COMPILE TIME (HPMAX) with a block-uniform runtime
// guard, so all acc[] indices are static and accumulators stay in VGPRs.
// Ps [32][128] (26 KB LDS total) -> 6 blocks/CU.
// ---------------------------------------------------------------------------
struct AttnShared {
    unsigned short BVs[8192];       // K tiles; V reuses the region in PV
    unsigned short Ps[32 * 128];    // one kcol-half of P
    float red0[32][5];
    float red1[32][5];
};

template<int NN, int NRB, bool IMP>
__device__ __forceinline__
void attn_body(const unsigned short* __restrict__ Qt, const unsigned short* __restrict__ Kt,
               const unsigned short* __restrict__ Vt, unsigned short* __restrict__ O,
               const int* __restrict__ aidx, const int* __restrict__ bidx,
               const int* __restrict__ rlen, const int* __restrict__ cln,
               float* __restrict__ imp_c, float* __restrict__ imp_p_part,
               AttnShared& sh, int lid)
{
    constexpr int MB = 32;
    constexpr int QI = 2;
    constexpr int KI = NN / 64;
    constexpr int NCH = NN / 32;
    constexpr int Mfull = MB * NRB;
    constexpr int HPMAX = (NN == 256) ? 2 : 1;
    constexpr int KH = KI / HPMAX;

    const int t = threadIdx.x;
    const int wid = t >> 6, l = t & 63, g = l >> 4, lr = l & 15;
    const int xcd = lid & 7;
    const int j = lid >> 3;
    const int rowblk = j % NRB;
    const int bz = (j / NRB) * 8 + xcd;
    const int rbase = rowblk * MB;
    const int rl = rlen[bz], cl_ = cln[bz];

    if (rbase >= rl) return;   // whole row-block masked: outputs never read

    // interleaved tile -> kcol mapping, ordered so tiles of half hp are
    // ki in [hp*KH, (hp+1)*KH): kbase = (hp*128) + (kk*4 + wid)*16 for cp.
    int kbase[KI];
    bool kneed[KI];
#pragma unroll
    for (int p = 0; p < KI; ++p) {
        int hp = p / KH, kk = p % KH;
        kbase[p] = hp * 128 + (kk * 4 + wid) * 16;
        kneed[p] = kbase[p] < cl_;
    }

    const unsigned short* kp[KI];
#pragma unroll
    for (int p = 0; p < KI; ++p) {
        int c = kbase[p] + (l >> 2);
        kp[p] = Kt + (size_t)bidx[bz * NN + c] * 768 + (((l & 3) ^ (c & 3)) << 3);
    }
    const unsigned short* qp[QI];
#pragma unroll
    for (int qi = 0; qi < QI; ++qi)
        qp[qi] = Qt + (size_t)aidx[bz * Mfull + rbase + qi * 16 + lr] * 768 + g * 8;

    auto stageK = [&](int k0) {
#pragma unroll
        for (int p = 0; p < KI; ++p)
            if (kneed[p])
                gld_lds16(kp[p] + k0, &sh.BVs[kbase[p] * 32 + l * 8]);
    };

    f32x4 acc[KI][QI];
#pragma unroll
    for (int ki = 0; ki < KI; ++ki)
#pragma unroll
        for (int qi = 0; qi < QI; ++qi) acc[ki][qi] = (f32x4){0.f, 0.f, 0.f, 0.f};

    short8 afb[2][QI];
    stageK(0);
#pragma unroll
    for (int qi = 0; qi < QI; ++qi) afb[0][qi] = *(const short8*)(qp[qi]);

    // ---- QK loop: single-buffered, self-paced (TLP hides latency) ----
#pragma unroll
    for (int it = 0; it < 8; ++it) {
        const int cur = it & 1;
        asm volatile("s_waitcnt vmcnt(0)" ::: "memory");
        __builtin_amdgcn_sched_barrier(0);
        short8 bf[KI];
#pragma unroll
        for (int ki = 0; ki < KI; ++ki)
            if (kneed[ki]) {
                int c = kbase[ki] + lr;
                bf[ki] = *(const short8*)&sh.BVs[c * 32 + ((g ^ (c & 3)) << 3)];
            }
        if (it < 7) {
            asm volatile("s_waitcnt lgkmcnt(0)" ::: "memory");
            __builtin_amdgcn_sched_barrier(0);
            stageK((it + 1) * 32);
#pragma unroll
            for (int qi = 0; qi < QI; ++qi)
                afb[cur ^ 1][qi] = *(const short8*)(qp[qi] + (it + 1) * 32);
        }
#pragma unroll
        for (int ki = 0; ki < KI; ++ki)
            if (kneed[ki])
#pragma unroll
                for (int qi = 0; qi < QI; ++qi)
                    acc[ki][qi] = __builtin_amdgcn_mfma_f32_16x16x32_bf16(bf[ki], afb[cur][qi], acc[ki][qi], 0, 0, 0);
    }

    // ---- issue V chunk-0 gathers (fly under softmax); wave-private dims ----
    const int va = l & 15, vcb = wid * 64 + (l >> 4) * 16;
    ushort8 v0a, v0b, v1a, v1b;
    {
        const unsigned short* q0 = Vt + (size_t)bidx[bz * NN + 2 * va] * 768 + vcb;
        const unsigned short* q1 = Vt + (size_t)bidx[bz * NN + 2 * va + 1] * 768 + vcb;
        v0a = *(const ushort8*)q0; v0b = *(const ushort8*)(q0 + 8);
        v1a = *(const ushort8*)q1; v1b = *(const ushort8*)(q1 + 8);
    }
    auto writeV = [&]() {
        int gg = va >> 2, kl = (2 * va) & 7;
#pragma unroll
        for (int e = 0; e < 8; ++e) {
            int c = vcb + e;
            *(unsigned*)&sh.BVs[c * 32 + ((gg ^ (c & 3)) << 3) + kl] =
                (unsigned)(unsigned short)v0a[e] | ((unsigned)(unsigned short)v1a[e] << 16);
        }
#pragma unroll
        for (int e = 0; e < 8; ++e) {
            int c = vcb + 8 + e;
            *(unsigned*)&sh.BVs[c * 32 + ((gg ^ (c & 3)) << 3) + kl] =
                (unsigned)(unsigned short)v0b[e] | ((unsigned)(unsigned short)v1b[e] << 16);
        }
    };

    // ---- mask + scale (covers skipped tiles: their acc==0 -> -1e9) ----
#pragma unroll
    for (int ki = 0; ki < KI; ++ki)
#pragma unroll
        for (int qi = 0; qi < QI; ++qi)
#pragma unroll
            for (int q = 0; q < 4; ++q) {
                int kcol = kbase[ki] + g * 4 + q;
                int qrow = rbase + qi * 16 + lr;
                acc[ki][qi][q] = (qrow < rl && kcol < cl_) ? acc[ki][qi][q] * 0.0625f : -1e9f;
            }

    // ---- row max ----
    float mx[QI], inv[QI];
#pragma unroll
    for (int qi = 0; qi < QI; ++qi) {
        float m = -1e30f;
#pragma unroll
        for (int ki = 0; ki < KI; ++ki)
#pragma unroll
            for (int q = 0; q < 4; ++q) m = fmaxf(m, acc[ki][qi][q]);
        m = fmaxf(m, __shfl_xor(m, 16));
        m = fmaxf(m, __shfl_xor(m, 32));
        mx[qi] = m;
    }
    if (g == 0)
#pragma unroll
        for (int qi = 0; qi < QI; ++qi) sh.red0[qi * 16 + lr][wid] = mx[qi];
    __syncthreads();   // B1 (all QK LDS reads complete block-wide)
#pragma unroll
    for (int qi = 0; qi < QI; ++qi) {
        int row = qi * 16 + lr;
        mx[qi] = fmaxf(fmaxf(sh.red0[row][0], sh.red0[row][1]), fmaxf(sh.red0[row][2], sh.red0[row][3]));
    }

    // ---- exp + row sum ----
#pragma unroll
    for (int qi = 0; qi < QI; ++qi) {
        float s = 0.f;
#pragma unroll
        for (int ki = 0; ki < KI; ++ki)
#pragma unroll
            for (int q = 0; q < 4; ++q) {
                float e = exp2f((acc[ki][qi][q] - mx[qi]) * L2E);
                acc[ki][qi][q] = e;
                s += e;
            }
        s += __shfl_xor(s, 16);
        s += __shfl_xor(s, 32);
        mx[qi] = s;
    }
    if (g == 0)
#pragma unroll
        for (int qi = 0; qi < QI; ++qi) sh.red1[qi * 16 + lr][wid] = mx[qi];
    writeV();          // V chunk 0 (post-B1, wave-private region)
    __syncthreads();   // B2
#pragma unroll
    for (int qi = 0; qi < QI; ++qi) {
        int row = qi * 16 + lr;
        inv[qi] = 1.f / (sh.red1[row][0] + sh.red1[row][1] + sh.red1[row][2] + sh.red1[row][3]);
    }

    if constexpr (IMP) {
        if (wid == 0 && g == 0)
#pragma unroll
            for (int qi = 0; qi < QI; ++qi)
                imp_c[bz * Mfull + rbase + qi * 16 + lr] = inv[qi];
#pragma unroll
        for (int ki = 0; ki < KI; ++ki)
#pragma unroll
            for (int q = 0; q < 4; ++q) {
                float m = -1e30f;
#pragma unroll
                for (int qi = 0; qi < QI; ++qi) {
                    bool vr = (rbase + qi * 16 + lr) < rl;
                    m = fmaxf(m, vr ? acc[ki][qi][q] * inv[qi] : -1e30f);
                }
#pragma unroll
                for (int o = 1; o < 16; o <<= 1) m = fmaxf(m, __shfl_xor(m, o));
                if (lr == 0) {
                    int kcol = kbase[ki] + g * 4 + q;
                    imp_p_part[((size_t)rowblk * NB + bz) * NN + kcol] = m;
                }
            }
    }

    // ---- PV over kcol halves, COMPILE-TIME unrolled (rule #20) ----
    const int NCHv = ((cl_ + 31) >> 5) < NCH ? ((cl_ + 31) >> 5) : NCH;
    const int hpmax = (NCHv + 3) >> 2;   // block-uniform: barriers inside guard OK

    f32x4 acc2[4][QI];
#pragma unroll
    for (int di = 0; di < 4; ++di)
#pragma unroll
        for (int qi = 0; qi < QI; ++qi) acc2[di][qi] = (f32x4){0.f, 0.f, 0.f, 0.f};

#pragma unroll
    for (int hp = 0; hp < HPMAX; ++hp) {
        if (hp < hpmax) {   // block-uniform guard
            // pack this half's P tiles (all indices compile-time)
#pragma unroll
            for (int kk = 0; kk < KH; ++kk) {
#pragma unroll
                for (int qi = 0; qi < QI; ++qi) {
                    int row = qi * 16 + lr;
                    int slot = ((kbase[hp * KH + kk] >> 2) & 31) + g;
                    int slotp = slot ^ ((lr & 7) << 1);
                    ushort4v pk;
                    pk.x = f2b(acc[hp * KH + kk][qi][0] * inv[qi]);
                    pk.y = f2b(acc[hp * KH + kk][qi][1] * inv[qi]);
                    pk.z = f2b(acc[hp * KH + kk][qi][2] * inv[qi]);
                    pk.w = f2b(acc[hp * KH + kk][qi][3] * inv[qi]);
                    *(ushort4v*)&sh.Ps[row * 128 + slotp * 4] = pk;
                }
            }
            __syncthreads();   // P half visible

            const int chEnd = ((hp + 1) * 4 < NCHv) ? (hp + 1) * 4 : NCHv;
            for (int ch = hp * 4; ch < chEnd; ++ch) {
                if (ch + 1 < NCHv) {
                    const unsigned short* q0 = Vt + (size_t)bidx[bz * NN + (ch + 1) * 32 + 2 * va] * 768 + vcb;
                    const unsigned short* q1 = Vt + (size_t)bidx[bz * NN + (ch + 1) * 32 + 2 * va + 1] * 768 + vcb;
                    v0a = *(const ushort8*)q0; v0b = *(const ushort8*)(q0 + 8);
                    v1a = *(const ushort8*)q1; v1b = *(const ushort8*)(q1 + 8);
                }
                short8 pf[QI], vf[4];
                const int chl = ch & 3;
#pragma unroll
                for (int qi = 0; qi < QI; ++qi) {
                    int row = qi * 16 + lr;
                    int slotr = (chl * 8 + 2 * g) ^ ((lr & 7) << 1);
                    pf[qi] = *(const short8*)&sh.Ps[row * 128 + slotr * 4];
                }
#pragma unroll
                for (int di = 0; di < 4; ++di) {
                    int c = wid * 64 + di * 16 + lr;
                    vf[di] = *(const short8*)&sh.BVs[c * 32 + ((g ^ (c & 3)) << 3)];
                }
#pragma unroll
                for (int di = 0; di < 4; ++di)
#pragma unroll
                    for (int qi = 0; qi < QI; ++qi)
                        acc2[di][qi] = __builtin_amdgcn_mfma_f32_16x16x32_bf16(vf[di], pf[qi], acc2[di][qi], 0, 0, 0);
                if (ch + 1 < NCHv) {
                    asm volatile("s_waitcnt lgkmcnt(0)" ::: "memory");
                    __builtin_amdgcn_sched_barrier(0);
                    writeV();
                }
            }
            if (hp + 1 < HPMAX && hp + 1 < hpmax) __syncthreads();   // before repack
        }
    }

    // ---- packed fused-output stores ----
#pragma unroll
    for (int di = 0; di < 4; ++di)
#pragma unroll
        for (int qi = 0; qi < QI; ++qi) {
            int qrow = qi * 16 + lr;
            int dim = wid * 64 + di * 16 + g * 4;
            ushort4v pk;
            pk.x = f2b(acc2[di][qi][0]);
            pk.y = f2b(acc2[di][qi][1]);
            pk.z = f2b(acc2[di][qi][2]);
            pk.w = f2b(acc2[di][qi][3]);
            *(ushort4v*)&O[((size_t)bz * Mfull + rbase + qrow) * 256 + dim] = pk;
        }
}

// Both attention directions in ONE dispatch, 6 blocks/CU.
__global__ __launch_bounds__(256, 6)
void attn_both(const unsigned short* __restrict__ tabC, const unsigned short* __restrict__ tabP,
               unsigned short* __restrict__ cfused, unsigned short* __restrict__ pfused,
               const int* __restrict__ comp_idx, const int* __restrict__ prot_idx,
               const int* __restrict__ comp_lens, const int* __restrict__ prot_lens,
               float* __restrict__ imp_c, float* __restrict__ imp_p_part)
{
    __shared__ AttnShared sh;
    const int lid = blockIdx.x;
    if (lid < 4 * NB)
        attn_body<256, 4, true>(tabC, tabP + 256, tabP + 512, cfused,
            comp_idx, prot_idx, comp_lens, prot_lens, imp_c, imp_p_part, sh, lid);
    else
        attn_body<128, 8, false>(tabP, tabC + 256, tabC + 512, pfused,
            prot_idx, comp_idx, prot_lens, comp_lens, nullptr, nullptr, sh, lid - 4 * NB);
}

__device__ __forceinline__ float br_max(float v, float* red)
{
#pragma unroll
    for (int o = 32; o; o >>= 1) v = fmaxf(v, __shfl_xor(v, o));
    __syncthreads();
    if ((threadIdx.x & 63) == 0) red[threadIdx.x >> 6] = v;
    __syncthreads();
    return fmaxf(fmaxf(red[0], red[1]), fmaxf(red[2], red[3]));
}

__device__ __forceinline__ float br_sum(float v, float* red)
{
#pragma unroll
    for (int o = 32; o; o >>= 1) v += __shfl_xor(v, o);
    __syncthreads();
    if ((threadIdx.x & 63) == 0) red[threadIdx.x >> 6] = v;
    __syncthreads();
    return red[0] + red[1] + red[2] + red[3];
}

__global__ __launch_bounds__(256)
void pool_kernel(const unsigned short* __restrict__ cg, const unsigned short* __restrict__ pg,
                 const float* __restrict__ imp_c, const float* __restrict__ imp_p_part,
                 const int* __restrict__ clens, const int* __restrict__ plens,
                 float* __restrict__ out)
{
    int b = blockIdx.x, t = threadIdx.x;
    __shared__ float w[256];
    __shared__ float red[4];
    int cl = clens[b], pl = plens[b];

    float x = (t < 128 && t < cl) ? imp_c[b * MC + t] : -1e30f;
    float mx = br_max(x, red);
    float e = (t < 128) ? exp2f((x - mx) * L2E) : 0.f;
    float s = br_sum(e, red);
    if (t < 128) w[t] = e / s;
    __syncthreads();

    float hv = 0.f;
    for (int n = 0; n < cl; ++n)
        hv += w[n] * b2f(cg[((size_t)b * MC + n) * 256 + t]);
    __syncthreads();

    const int nv = (cl + 31) >> 5;
    float x2 = -1e30f;
    if (t < pl) {
        x2 = imp_p_part[(size_t)b * MP + t];
        for (int jj = 1; jj < nv; ++jj)
            x2 = fmaxf(x2, imp_p_part[(size_t)(jj * NB + b) * MP + t]);
    }
    float mx2 = br_max(x2, red);
    float e2 = exp2f((x2 - mx2) * L2E);
    float s2 = br_sum(e2, red);
    w[t] = e2 / s2;
    __syncthreads();

    float dv = 0.f;
    for (int m = 0; m < pl; ++m)
        dv += w[m] * b2f(pg[((size_t)b * MP + m) * 256 + t]);

    float logit = br_sum(hv * dv, red);
    if (t == 0) out[b] = 1.f / (1.f + expf(-logit));
}

// ---------------------------------------------------------------------------
extern "C" void kernel_launch(void* const* d_in, const int* in_sizes, int n_in,
                              void* d_out, int out_size, void* d_ws, size_t ws_size,
                              hipStream_t stream)
{
    const float* comp_emb = (const float*)d_in[0];
    const float* prot_emb = (const float*)d_in[1];
    const int* comp_idx  = (const int*)d_in[18];
    const int* prot_idx  = (const int*)d_in[19];
    const int* comp_lens = (const int*)d_in[20];
    const int* prot_lens = (const int*)d_in[21];
    float* out = (float*)d_out;

    const int N_C = in_sizes[0] / 256;
    const int N_P = in_sizes[1] / 256;
    const size_t NTc = (size_t)N_C * 256;
    const size_t NTp = (size_t)N_P * 256;

    // ---- workspace layout (bf16 elems) ----
    unsigned short* comp_bf = (unsigned short*)d_ws;
    unsigned short* prot_bf = comp_bf + NTc;
    unsigned short* Wcat    = prot_bf + NTp;                 // [2048][256]
    float* bias_cat         = (float*)(Wcat + 2048 * 256);   // [2048]
    unsigned short* tabC    = (unsigned short*)(bias_cat + 2048);  // [N_C][768] q|k|v
    unsigned short* tabP    = tabC + (size_t)N_C * 768;            // [N_P][768] q|k|v
    unsigned short* cfused  = tabP + (size_t)N_P * 768;      // [NB][128][256]
    unsigned short* pfused  = cfused + (size_t)NB * MC * 256; // [NB][256][256] (contiguous)
    float* imp_c      = (float*)(pfused + (size_t)NB * MP * 256);
    float* imp_p_part = imp_c + NB * MC;                     // [4][NB][256]

    // ---- conversions ----
    cvt_f32_bf16<<<dim3(2048), 256, 0, stream>>>(comp_emb, comp_bf, (int)(NTc / 4));
    cvt_f32_bf16<<<dim3(2048), 256, 0, stream>>>(prot_emb, prot_bf, (int)(NTp / 4));
    cvt_weights8<<<dim3(64, 8), 256, 0, stream>>>(
        (const float*)d_in[2], (const float*)d_in[4], (const float*)d_in[6], (const float*)d_in[14],
        (const float*)d_in[8], (const float*)d_in[10], (const float*)d_in[12], (const float*)d_in[16],
        (const float*)d_in[3], (const float*)d_in[5], (const float*)d_in[7], (const float*)d_in[15],
        (const float*)d_in[9], (const float*)d_in[11], (const float*)d_in[13], (const float*)d_in[17],
        Wcat, bias_cat);

    const int gpc = (N_C + 127) / 128, gpp = (N_P + 127) / 128;

    // ---- merged qkv projection (both sides, one dispatch) ----
    proj_qkv<<<dim3(gpc + gpp, 6), 256, 0, stream>>>(comp_bf, prot_bf, Wcat, bias_cat,
        tabC, tabP, N_C, N_P, gpc);

    // ---- merged attention (ragged skips, 6 blocks/CU, static indexing) ----
    attn_both<<<dim3(4 * NB + 8 * NB), 256, 0, stream>>>(
        tabC, tabP, cfused, pfused,
        comp_idx, prot_idx, comp_lens, prot_lens, imp_c, imp_p_part);

    // ---- merged sigmoid gating (both tensors, ragged row skip) ----
    gate_both<<<dim3((NB * MC + NB * MP) / 64), 256, 0, stream>>>(cfused, Wcat, bias_cat,
        comp_lens, prot_lens);

    // ---- pooling + logit (bounded loops) ----
    pool_kernel<<<dim3(NB), 256, 0, stream>>>(cfused, pfused, imp_c, imp_p_part, comp_lens, prot_lens, out);
}

// Round 20
// 174.764 us; speedup vs baseline: 1.2304x; 1.0491x over previous
//
#include <hip/hip_runtime.h>
#include <cstdint>

typedef __attribute__((ext_vector_type(8))) short short8;
typedef __attribute__((ext_vector_type(8))) unsigned short ushort8;
typedef __attribute__((ext_vector_type(4))) unsigned short ushort4v;
typedef __attribute__((ext_vector_type(4))) float f32x4;

constexpr int NB = 256, MC = 128, MP = 256;
constexpr float L2E = 1.442695041f;

__device__ __forceinline__ float b2f(unsigned short h) { return __uint_as_float(((unsigned)h) << 16); }
__device__ __forceinline__ unsigned short f2b(float f) {
    unsigned u = __float_as_uint(f);
    u += 0x7fffu + ((u >> 16) & 1u);
    return (unsigned short)(u >> 16);
}
__device__ __forceinline__ float sigmoid_f(float x) {
    return __builtin_amdgcn_rcpf(1.f + exp2f(-L2E * x));
}
__device__ __forceinline__ void gld_lds16(const unsigned short* g, unsigned short* l) {
    __builtin_amdgcn_global_load_lds((const __attribute__((address_space(1))) void*)g,
                                     (__attribute__((address_space(3))) void*)l, 16, 0, 0);
}

__global__ __launch_bounds__(256)
void cvt_f32_bf16(const float* __restrict__ in, unsigned short* __restrict__ out, int n4) {
    int i = blockIdx.x * 256 + threadIdx.x;
    int stride = gridDim.x * 256;
    for (; i < n4; i += stride) {
        float4 v = ((const float4*)in)[i];
        ushort4v o;
        o.x = f2b(v.x); o.y = f2b(v.y); o.z = f2b(v.z); o.w = f2b(v.w);
        ((ushort4v*)out)[i] = o;
    }
}

// 8 weights -> Wcat [2048][256] bf16 + bias_cat[2048] f32.
// Row-block order: q_c,k_c,v_c,g_c,q_p,k_p,v_p,g_p (qkv contiguous per side).
__global__ __launch_bounds__(256)
void cvt_weights8(const float* w0, const float* w1, const float* w2, const float* w3,
                  const float* w4, const float* w5, const float* w6, const float* w7,
                  const float* b0, const float* b1, const float* b2, const float* b3,
                  const float* b4, const float* b5, const float* b6, const float* b7,
                  unsigned short* __restrict__ Wcat, float* __restrict__ bias_cat)
{
    const float* wsel[8] = {w0, w1, w2, w3, w4, w5, w6, w7};
    const float* bsel[8] = {b0, b1, b2, b3, b4, b5, b6, b7};
    int j = blockIdx.y;
    int i = blockIdx.x * 256 + threadIdx.x;
    float4 v = ((const float4*)wsel[j])[i];
    ushort4v o;
    o.x = f2b(v.x); o.y = f2b(v.y); o.z = f2b(v.z); o.w = f2b(v.w);
    ((ushort4v*)(Wcat + (size_t)j * 65536))[i] = o;
    if (blockIdx.x == 0) bias_cat[j * 256 + threadIdx.x] = bsel[j][threadIdx.x];
}

// ---------------------------------------------------------------------------
// Merged QKV projection (both entity sides in ONE dispatch), bf16 source.
// ---------------------------------------------------------------------------
__global__ __launch_bounds__(256, 4)
void proj_qkv(const unsigned short* __restrict__ comp_bf, const unsigned short* __restrict__ prot_bf,
              const unsigned short* __restrict__ Wcat, const float* __restrict__ bias_cat,
              unsigned short* __restrict__ tabC, unsigned short* __restrict__ tabP,
              int N_C, int N_P, int gpc)
{
    __shared__ __align__(16) unsigned short As[2][128 * 32];
    __shared__ __align__(16) unsigned short Bs[2][128 * 32];

    const bool isP = (int)blockIdx.x >= gpc;
    const unsigned short* A = isP ? prot_bf : comp_bf;
    unsigned short* C = isP ? tabP : tabC;
    const unsigned short* W = Wcat + (isP ? (size_t)1024 * 256 : 0);
    const float* bias = bias_cat + (isP ? 1024 : 0);
    const int M = isP ? N_P : N_C;
    const int bx = isP ? (int)blockIdx.x - gpc : (int)blockIdx.x;

    const int t = threadIdx.x;
    const int wid = t >> 6, l = t & 63, g = l >> 4, lr = l & 15;
    const int wrb = (wid >> 1) * 64, wcb = (wid & 1) * 64;
    const int r0 = bx * 128, c0 = blockIdx.y * 128;

    f32x4 acc[4][4];
#pragma unroll
    for (int mi = 0; mi < 4; ++mi)
#pragma unroll
        for (int ni = 0; ni < 4; ++ni) acc[mi][ni] = (f32x4){0.f, 0.f, 0.f, 0.f};

    auto stage = [&](int buf, int k0) {
#pragma unroll
        for (int p = 0; p < 2; ++p) {
            int i = p * 256 + t;
            int r = i >> 2, s = i & 3;
            int gr = r0 + r; if (gr >= M) gr = M - 1;
            gld_lds16(A + (size_t)gr * 256 + k0 + ((s ^ (r & 3)) << 3), &As[buf][i * 8]);
        }
#pragma unroll
        for (int p = 0; p < 2; ++p) {
            int i = p * 256 + t;
            int c = i >> 2, s = i & 3;
            gld_lds16(W + (size_t)(c0 + c) * 256 + k0 + ((s ^ (c & 3)) << 3), &Bs[buf][i * 8]);
        }
    };

    stage(0, 0);
    __syncthreads();
#pragma unroll
    for (int it = 0; it < 8; ++it) {
        const int cur = it & 1;
        if (it + 1 < 8) stage(cur ^ 1, (it + 1) << 5);
        short8 af[4], bfr[4];
#pragma unroll
        for (int mi = 0; mi < 4; ++mi) {
            int r = wrb + mi * 16 + lr;
            af[mi] = *(const short8*)&As[cur][r * 32 + ((g ^ (r & 3)) << 3)];
        }
#pragma unroll
        for (int ni = 0; ni < 4; ++ni) {
            int c = wcb + ni * 16 + lr;
            bfr[ni] = *(const short8*)&Bs[cur][c * 32 + ((g ^ (c & 3)) << 3)];
        }
#pragma unroll
        for (int mi = 0; mi < 4; ++mi)
#pragma unroll
            for (int ni = 0; ni < 4; ++ni)
                acc[mi][ni] = __builtin_amdgcn_mfma_f32_16x16x32_bf16(af[mi], bfr[ni], acc[mi][ni], 0, 0, 0);
        if (it + 1 < 8) __syncthreads();
    }

#pragma unroll
    for (int mi = 0; mi < 4; ++mi)
#pragma unroll
        for (int ni = 0; ni < 4; ++ni)
#pragma unroll
            for (int q = 0; q < 4; ++q) {
                int gr = r0 + wrb + mi * 16 + g * 4 + q;
                int gc = c0 + wcb + ni * 16 + lr;
                if (gr < M) C[(size_t)gr * 768 + gc] = f2b(acc[mi][ni][q] + bias[gc]);
            }
}

// ---------------------------------------------------------------------------
// Merged sigmoid gating with ragged ROW SKIP.
// ---------------------------------------------------------------------------
__global__ __launch_bounds__(256, 4)
void gate_both(unsigned short* __restrict__ F, const unsigned short* __restrict__ Wcat,
               const float* __restrict__ bias_cat,
               const int* __restrict__ clens, const int* __restrict__ plens)
{
    const int r0 = blockIdx.x * 64;
    const bool isP = r0 >= NB * MC;
    int bz, local;
    if (isP) { int rr = r0 - NB * MC; bz = rr >> 8; local = rr & 255; }
    else     { bz = r0 >> 7; local = r0 & 127; }
    const int len = isP ? plens[bz] : clens[bz];
    if (local >= len) return;   // all 64 rows masked -> outputs never read

    __shared__ __align__(16) unsigned short As[2][64 * 32];
    __shared__ __align__(16) unsigned short Bs[2][256 * 32];

    const int t = threadIdx.x;
    const int wid = t >> 6, l = t & 63, g = l >> 4, lr = l & 15;
    const unsigned short* W = Wcat + (size_t)(isP ? 1792 : 768) * 256;
    const float* bias = bias_cat + (isP ? 1792 : 768);
    const int wcb = wid * 64;

    f32x4 acc[4][4];
#pragma unroll
    for (int mi = 0; mi < 4; ++mi)
#pragma unroll
        for (int ni = 0; ni < 4; ++ni) acc[mi][ni] = (f32x4){0.f, 0.f, 0.f, 0.f};

    auto stage = [&](int buf, int k0) {
        {
            int i = t;
            int r = i >> 2, s = i & 3;
            gld_lds16(F + (size_t)(r0 + r) * 256 + k0 + ((s ^ (r & 3)) << 3), &As[buf][i * 8]);
        }
#pragma unroll
        for (int p = 0; p < 4; ++p) {
            int i = p * 256 + t;
            int c = i >> 2, s = i & 3;
            gld_lds16(W + (size_t)c * 256 + k0 + ((s ^ (c & 3)) << 3), &Bs[buf][i * 8]);
        }
    };

    stage(0, 0);
    __syncthreads();
#pragma unroll
    for (int it = 0; it < 8; ++it) {
        const int cur = it & 1;
        if (it + 1 < 8) stage(cur ^ 1, (it + 1) << 5);
        short8 af[4], bfr[4];
#pragma unroll
        for (int mi = 0; mi < 4; ++mi) {
            int r = mi * 16 + lr;
            af[mi] = *(const short8*)&As[cur][r * 32 + ((g ^ (r & 3)) << 3)];
        }
#pragma unroll
        for (int ni = 0; ni < 4; ++ni) {
            int c = wcb + ni * 16 + lr;
            bfr[ni] = *(const short8*)&Bs[cur][c * 32 + ((g ^ (c & 3)) << 3)];
        }
#pragma unroll
        for (int mi = 0; mi < 4; ++mi)
#pragma unroll
            for (int ni = 0; ni < 4; ++ni)
                acc[mi][ni] = __builtin_amdgcn_mfma_f32_16x16x32_bf16(af[mi], bfr[ni], acc[mi][ni], 0, 0, 0);
        if (it + 1 < 8) __syncthreads();
    }

#pragma unroll
    for (int mi = 0; mi < 4; ++mi)
#pragma unroll
        for (int ni = 0; ni < 4; ++ni)
#pragma unroll
            for (int q = 0; q < 4; ++q) {
                int gr = r0 + mi * 16 + g * 4 + q;
                int gc = wcb + ni * 16 + lr;
                size_t o = (size_t)gr * 256 + gc;
                F[o] = f2b(b2f(F[o]) * sigmoid_f(acc[mi][ni][q] + bias[gc]));
            }
}

// ---------------------------------------------------------------------------
// Mega-fused attention (R17 structure: 34 KB LDS, 4 blocks/CU, interleaved
// K-tile mapping, ragged skips) + SINGLE-BARRIER flash-style softmax merge:
// each wave computes local (m_w, s_w), writes the pair, ONE barrier, then
// combines s = sum_w s_w*exp2(m_w-m) and folds exp2(m_w-m)/s into a per-
// (wave,row) factor fw used at imp/pack time. Removes one block barrier
// and one LDS round-trip vs R17. Identical math (masked rows -> uniform).
// ---------------------------------------------------------------------------
struct AttnShared {
    unsigned short BVs[8192];
    unsigned short Ps[32 * 256];
    float red0[32][5];   // per-wave row max
    float red1[32][5];   // per-wave row sum (local-max referenced)
};

template<int NN, int NRB, bool IMP>
__device__ __forceinline__
void attn_body(const unsigned short* __restrict__ Qt, const unsigned short* __restrict__ Kt,
               const unsigned short* __restrict__ Vt, unsigned short* __restrict__ O,
               const int* __restrict__ aidx, const int* __restrict__ bidx,
               const int* __restrict__ rlen, const int* __restrict__ cln,
               float* __restrict__ imp_c, float* __restrict__ imp_p_part,
               AttnShared& sh, int lid)
{
    constexpr int MB = 32;
    constexpr int QI = 2;
    constexpr int KI = NN / 64;
    constexpr int NCH = NN / 32;
    constexpr int Mfull = MB * NRB;

    const int t = threadIdx.x;
    const int wid = t >> 6, l = t & 63, g = l >> 4, lr = l & 15;
    const int xcd = lid & 7;
    const int j = lid >> 3;
    const int rowblk = j % NRB;
    const int bz = (j / NRB) * 8 + xcd;
    const int rbase = rowblk * MB;
    const int rl = rlen[bz], cl_ = cln[bz];

    if (rbase >= rl) return;   // whole row-block masked: outputs never read

    // interleaved tile -> kcol mapping
    int kbase[KI];
    bool kneed[KI];
#pragma unroll
    for (int p = 0; p < KI; ++p) {
        kbase[p] = (p * 4 + wid) * 16;
        kneed[p] = kbase[p] < cl_;
    }

    const unsigned short* kp[KI];
#pragma unroll
    for (int p = 0; p < KI; ++p) {
        int c = kbase[p] + (l >> 2);
        kp[p] = Kt + (size_t)bidx[bz * NN + c] * 768 + (((l & 3) ^ (c & 3)) << 3);
    }
    const unsigned short* qp[QI];
#pragma unroll
    for (int qi = 0; qi < QI; ++qi)
        qp[qi] = Qt + (size_t)aidx[bz * Mfull + rbase + qi * 16 + lr] * 768 + g * 8;

    auto stageK = [&](int k0) {
#pragma unroll
        for (int p = 0; p < KI; ++p)
            if (kneed[p])
                gld_lds16(kp[p] + k0, &sh.BVs[kbase[p] * 32 + l * 8]);
    };

    f32x4 acc[KI][QI];
#pragma unroll
    for (int ki = 0; ki < KI; ++ki)
#pragma unroll
        for (int qi = 0; qi < QI; ++qi) acc[ki][qi] = (f32x4){0.f, 0.f, 0.f, 0.f};

    short8 afb[2][QI];
    stageK(0);
#pragma unroll
    for (int qi = 0; qi < QI; ++qi) afb[0][qi] = *(const short8*)(qp[qi]);

    // ---- QK loop: single-buffered, self-paced (TLP hides latency) ----
#pragma unroll
    for (int it = 0; it < 8; ++it) {
        const int cur = it & 1;
        asm volatile("s_waitcnt vmcnt(0)" ::: "memory");
        __builtin_amdgcn_sched_barrier(0);
        short8 bf[KI];
#pragma unroll
        for (int ki = 0; ki < KI; ++ki)
            if (kneed[ki]) {
                int c = kbase[ki] + lr;
                bf[ki] = *(const short8*)&sh.BVs[c * 32 + ((g ^ (c & 3)) << 3)];
            }
        if (it < 7) {
            asm volatile("s_waitcnt lgkmcnt(0)" ::: "memory");
            __builtin_amdgcn_sched_barrier(0);
            stageK((it + 1) * 32);
#pragma unroll
            for (int qi = 0; qi < QI; ++qi)
                afb[cur ^ 1][qi] = *(const short8*)(qp[qi] + (it + 1) * 32);
        }
#pragma unroll
        for (int ki = 0; ki < KI; ++ki)
            if (kneed[ki])
#pragma unroll
                for (int qi = 0; qi < QI; ++qi)
                    acc[ki][qi] = __builtin_amdgcn_mfma_f32_16x16x32_bf16(bf[ki], afb[cur][qi], acc[ki][qi], 0, 0, 0);
    }

    // ---- issue V chunk-0 gathers (fly under softmax); wave-private dims ----
    const int va = l & 15, vcb = wid * 64 + (l >> 4) * 16;
    ushort8 v0a, v0b, v1a, v1b;
    {
        const unsigned short* q0 = Vt + (size_t)bidx[bz * NN + 2 * va] * 768 + vcb;
        const unsigned short* q1 = Vt + (size_t)bidx[bz * NN + 2 * va + 1] * 768 + vcb;
        v0a = *(const ushort8*)q0; v0b = *(const ushort8*)(q0 + 8);
        v1a = *(const ushort8*)q1; v1b = *(const ushort8*)(q1 + 8);
    }
    auto writeV = [&]() {
        int gg = va >> 2, kl = (2 * va) & 7;
#pragma unroll
        for (int e = 0; e < 8; ++e) {
            int c = vcb + e;
            *(unsigned*)&sh.BVs[c * 32 + ((gg ^ (c & 3)) << 3) + kl] =
                (unsigned)(unsigned short)v0a[e] | ((unsigned)(unsigned short)v1a[e] << 16);
        }
#pragma unroll
        for (int e = 0; e < 8; ++e) {
            int c = vcb + 8 + e;
            *(unsigned*)&sh.BVs[c * 32 + ((gg ^ (c & 3)) << 3) + kl] =
                (unsigned)(unsigned short)v0b[e] | ((unsigned)(unsigned short)v1b[e] << 16);
        }
    };

    // ---- mask + scale (covers skipped tiles: their acc==0 -> -1e9) ----
#pragma unroll
    for (int ki = 0; ki < KI; ++ki)
#pragma unroll
        for (int qi = 0; qi < QI; ++qi)
#pragma unroll
            for (int q = 0; q < 4; ++q) {
                int kcol = kbase[ki] + g * 4 + q;
                int qrow = rbase + qi * 16 + lr;
                acc[ki][qi][q] = (qrow < rl && kcol < cl_) ? acc[ki][qi][q] * 0.0625f : -1e9f;
            }

    // ---- single-pass softmax: per-wave (m_w, s_w), ONE barrier, combine ----
    float mw[QI], fw[QI];
#pragma unroll
    for (int qi = 0; qi < QI; ++qi) {
        float m = -1e30f;
#pragma unroll
        for (int ki = 0; ki < KI; ++ki)
#pragma unroll
            for (int q = 0; q < 4; ++q) m = fmaxf(m, acc[ki][qi][q]);
        m = fmaxf(m, __shfl_xor(m, 16));
        m = fmaxf(m, __shfl_xor(m, 32));
        mw[qi] = m;
        float s = 0.f;
#pragma unroll
        for (int ki = 0; ki < KI; ++ki)
#pragma unroll
            for (int q = 0; q < 4; ++q) {
                float e = exp2f((acc[ki][qi][q] - m) * L2E);
                acc[ki][qi][q] = e;    // local-max referenced
                s += e;
            }
        s += __shfl_xor(s, 16);
        s += __shfl_xor(s, 32);
        fw[qi] = s;                    // temporarily local sum
    }
    if (g == 0)
#pragma unroll
        for (int qi = 0; qi < QI; ++qi) {
            sh.red0[qi * 16 + lr][wid] = mw[qi];
            sh.red1[qi * 16 + lr][wid] = fw[qi];
        }
    __syncthreads();   // B1: red pairs visible; all QK BVs reads complete
    writeV();          // V chunk 0 (safe post-B1)
    float invs[QI];
#pragma unroll
    for (int qi = 0; qi < QI; ++qi) {
        int row = qi * 16 + lr;
        float m0 = sh.red0[row][0], m1 = sh.red0[row][1];
        float m2 = sh.red0[row][2], m3 = sh.red0[row][3];
        float m = fmaxf(fmaxf(m0, m1), fmaxf(m2, m3));
        float s = sh.red1[row][0] * exp2f((m0 - m) * L2E)
                + sh.red1[row][1] * exp2f((m1 - m) * L2E)
                + sh.red1[row][2] * exp2f((m2 - m) * L2E)
                + sh.red1[row][3] * exp2f((m3 - m) * L2E);
        invs[qi] = 1.f / s;
        fw[qi] = exp2f((mw[qi] - m) * L2E) * invs[qi];  // fold rescale+norm
    }

    if constexpr (IMP) {
        if (wid == 0 && g == 0)
#pragma unroll
            for (int qi = 0; qi < QI; ++qi)
                imp_c[bz * Mfull + rbase + qi * 16 + lr] = invs[qi];
#pragma unroll
        for (int ki = 0; ki < KI; ++ki)
#pragma unroll
            for (int q = 0; q < 4; ++q) {
                float m = -1e30f;
#pragma unroll
                for (int qi = 0; qi < QI; ++qi) {
                    bool vr = (rbase + qi * 16 + lr) < rl;
                    m = fmaxf(m, vr ? acc[ki][qi][q] * fw[qi] : -1e30f);
                }
#pragma unroll
                for (int o = 1; o < 16; o <<= 1) m = fmaxf(m, __shfl_xor(m, o));
                if (lr == 0) {
                    int kcol = kbase[ki] + g * 4 + q;
                    imp_p_part[((size_t)rowblk * NB + bz) * NN + kcol] = m;
                }
            }
    }

    // ---- normalize + pack P into LDS (slot indexed by absolute kcol) ----
#pragma unroll
    for (int ki = 0; ki < KI; ++ki)
#pragma unroll
        for (int qi = 0; qi < QI; ++qi) {
            int row = qi * 16 + lr;
            int slot = (kbase[ki] >> 2) + g;
            int slotp = slot ^ ((lr & 7) << 1);
            ushort4v pk;
            pk.x = f2b(acc[ki][qi][0] * fw[qi]);
            pk.y = f2b(acc[ki][qi][1] * fw[qi]);
            pk.z = f2b(acc[ki][qi][2] * fw[qi]);
            pk.w = f2b(acc[ki][qi][3] * fw[qi]);
            *(ushort4v*)&sh.Ps[row * NN + slotp * 4] = pk;
        }
    __syncthreads();   // B2: Ps + V chunk 0 visible

    // ---- PV: chunk loop bounded by valid cols (P exactly 0 beyond) ----
    const int NCHv = ((cl_ + 31) >> 5) < NCH ? ((cl_ + 31) >> 5) : NCH;
    f32x4 acc2[4][QI];
#pragma unroll
    for (int di = 0; di < 4; ++di)
#pragma unroll
        for (int qi = 0; qi < QI; ++qi) acc2[di][qi] = (f32x4){0.f, 0.f, 0.f, 0.f};

    for (int ch = 0; ch < NCHv; ++ch) {
        if (ch + 1 < NCHv) {
            const unsigned short* q0 = Vt + (size_t)bidx[bz * NN + (ch + 1) * 32 + 2 * va] * 768 + vcb;
            const unsigned short* q1 = Vt + (size_t)bidx[bz * NN + (ch + 1) * 32 + 2 * va + 1] * 768 + vcb;
            v0a = *(const ushort8*)q0; v0b = *(const ushort8*)(q0 + 8);
            v1a = *(const ushort8*)q1; v1b = *(const ushort8*)(q1 + 8);
        }
        short8 pf[QI], vf[4];
#pragma unroll
        for (int qi = 0; qi < QI; ++qi) {
            int row = qi * 16 + lr;
            int slotr = (ch * 8 + 2 * g) ^ ((lr & 7) << 1);
            pf[qi] = *(const short8*)&sh.Ps[row * NN + slotr * 4];
        }
#pragma unroll
        for (int di = 0; di < 4; ++di) {
            int c = wid * 64 + di * 16 + lr;
            vf[di] = *(const short8*)&sh.BVs[c * 32 + ((g ^ (c & 3)) << 3)];
        }
#pragma unroll
        for (int di = 0; di < 4; ++di)
#pragma unroll
            for (int qi = 0; qi < QI; ++qi)
                acc2[di][qi] = __builtin_amdgcn_mfma_f32_16x16x32_bf16(vf[di], pf[qi], acc2[di][qi], 0, 0, 0);
        if (ch + 1 < NCHv) {
            asm volatile("s_waitcnt lgkmcnt(0)" ::: "memory");
            __builtin_amdgcn_sched_barrier(0);
            writeV();
        }
    }

    // ---- packed fused-output stores ----
#pragma unroll
    for (int di = 0; di < 4; ++di)
#pragma unroll
        for (int qi = 0; qi < QI; ++qi) {
            int qrow = qi * 16 + lr;
            int dim = wid * 64 + di * 16 + g * 4;
            ushort4v pk;
            pk.x = f2b(acc2[di][qi][0]);
            pk.y = f2b(acc2[di][qi][1]);
            pk.z = f2b(acc2[di][qi][2]);
            pk.w = f2b(acc2[di][qi][3]);
            *(ushort4v*)&O[((size_t)bz * Mfull + rbase + qrow) * 256 + dim] = pk;
        }
}

// Both attention directions in ONE dispatch.
__global__ __launch_bounds__(256, 4)
void attn_both(const unsigned short* __restrict__ tabC, const unsigned short* __restrict__ tabP,
               unsigned short* __restrict__ cfused, unsigned short* __restrict__ pfused,
               const int* __restrict__ comp_idx, const int* __restrict__ prot_idx,
               const int* __restrict__ comp_lens, const int* __restrict__ prot_lens,
               float* __restrict__ imp_c, float* __restrict__ imp_p_part)
{
    __shared__ AttnShared sh;
    const int lid = blockIdx.x;
    if (lid < 4 * NB)
        attn_body<256, 4, true>(tabC, tabP + 256, tabP + 512, cfused,
            comp_idx, prot_idx, comp_lens, prot_lens, imp_c, imp_p_part, sh, lid);
    else
        attn_body<128, 8, false>(tabP, tabC + 256, tabC + 512, pfused,
            prot_idx, comp_idx, prot_lens, comp_lens, nullptr, nullptr, sh, lid - 4 * NB);
}

__device__ __forceinline__ float br_max(float v, float* red)
{
#pragma unroll
    for (int o = 32; o; o >>= 1) v = fmaxf(v, __shfl_xor(v, o));
    __syncthreads();
    if ((threadIdx.x & 63) == 0) red[threadIdx.x >> 6] = v;
    __syncthreads();
    return fmaxf(fmaxf(red[0], red[1]), fmaxf(red[2], red[3]));
}

__device__ __forceinline__ float br_sum(float v, float* red)
{
#pragma unroll
    for (int o = 32; o; o >>= 1) v += __shfl_xor(v, o);
    __syncthreads();
    if ((threadIdx.x & 63) == 0) red[threadIdx.x >> 6] = v;
    __syncthreads();
    return red[0] + red[1] + red[2] + red[3];
}

__global__ __launch_bounds__(256)
void pool_kernel(const unsigned short* __restrict__ cg, const unsigned short* __restrict__ pg,
                 const float* __restrict__ imp_c, const float* __restrict__ imp_p_part,
                 const int* __restrict__ clens, const int* __restrict__ plens,
                 float* __restrict__ out)
{
    int b = blockIdx.x, t = threadIdx.x;
    __shared__ float w[256];
    __shared__ float red[4];
    int cl = clens[b], pl = plens[b];

    float x = (t < 128 && t < cl) ? imp_c[b * MC + t] : -1e30f;
    float mx = br_max(x, red);
    float e = (t < 128) ? exp2f((x - mx) * L2E) : 0.f;
    float s = br_sum(e, red);
    if (t < 128) w[t] = e / s;
    __syncthreads();

    float hv = 0.f;
    for (int n = 0; n < cl; ++n)
        hv += w[n] * b2f(cg[((size_t)b * MC + n) * 256 + t]);
    __syncthreads();

    const int nv = (cl + 31) >> 5;
    float x2 = -1e30f;
    if (t < pl) {
        x2 = imp_p_part[(size_t)b * MP + t];
        for (int jj = 1; jj < nv; ++jj)
            x2 = fmaxf(x2, imp_p_part[(size_t)(jj * NB + b) * MP + t]);
    }
    float mx2 = br_max(x2, red);
    float e2 = exp2f((x2 - mx2) * L2E);
    float s2 = br_sum(e2, red);
    w[t] = e2 / s2;
    __syncthreads();

    float dv = 0.f;
    for (int m = 0; m < pl; ++m)
        dv += w[m] * b2f(pg[((size_t)b * MP + m) * 256 + t]);

    float logit = br_sum(hv * dv, red);
    if (t == 0) out[b] = 1.f / (1.f + expf(-logit));
}

// ---------------------------------------------------------------------------
extern "C" void kernel_launch(void* const* d_in, const int* in_sizes, int n_in,
                              void* d_out, int out_size, void* d_ws, size_t ws_size,
                              hipStream_t stream)
{
    const float* comp_emb = (const float*)d_in[0];
    const float* prot_emb = (const float*)d_in[1];
    const int* comp_idx  = (const int*)d_in[18];
    const int* prot_idx  = (const int*)d_in[19];
    const int* comp_lens = (const int*)d_in[20];
    const int* prot_lens = (const int*)d_in[21];
    float* out = (float*)d_out;

    const int N_C = in_sizes[0] / 256;
    const int N_P = in_sizes[1] / 256;
    const size_t NTc = (size_t)N_C * 256;
    const size_t NTp = (size_t)N_P * 256;

    // ---- workspace layout (bf16 elems) ----
    unsigned short* comp_bf = (unsigned short*)d_ws;
    unsigned short* prot_bf = comp_bf + NTc;
    unsigned short* Wcat    = prot_bf + NTp;                 // [2048][256]
    float* bias_cat         = (float*)(Wcat + 2048 * 256);   // [2048]
    unsigned short* tabC    = (unsigned short*)(bias_cat + 2048);  // [N_C][768] q|k|v
    unsigned short* tabP    = tabC + (size_t)N_C * 768;            // [N_P][768] q|k|v
    unsigned short* cfused  = tabP + (size_t)N_P * 768;      // [NB][128][256]
    unsigned short* pfused  = cfused + (size_t)NB * MC * 256; // [NB][256][256] (contiguous)
    float* imp_c      = (float*)(pfused + (size_t)NB * MP * 256);
    float* imp_p_part = imp_c + NB * MC;                     // [4][NB][256]

    // ---- conversions ----
    cvt_f32_bf16<<<dim3(2048), 256, 0, stream>>>(comp_emb, comp_bf, (int)(NTc / 4));
    cvt_f32_bf16<<<dim3(2048), 256, 0, stream>>>(prot_emb, prot_bf, (int)(NTp / 4));
    cvt_weights8<<<dim3(64, 8), 256, 0, stream>>>(
        (const float*)d_in[2], (const float*)d_in[4], (const float*)d_in[6], (const float*)d_in[14],
        (const float*)d_in[8], (const float*)d_in[10], (const float*)d_in[12], (const float*)d_in[16],
        (const float*)d_in[3], (const float*)d_in[5], (const float*)d_in[7], (const float*)d_in[15],
        (const float*)d_in[9], (const float*)d_in[11], (const float*)d_in[13], (const float*)d_in[17],
        Wcat, bias_cat);

    const int gpc = (N_C + 127) / 128, gpp = (N_P + 127) / 128;

    // ---- merged qkv projection (both sides, one dispatch) ----
    proj_qkv<<<dim3(gpc + gpp, 6), 256, 0, stream>>>(comp_bf, prot_bf, Wcat, bias_cat,
        tabC, tabP, N_C, N_P, gpc);

    // ---- merged attention (ragged skips, interleaved tiles, 1-barrier SM) ----
    attn_both<<<dim3(4 * NB + 8 * NB), 256, 0, stream>>>(
        tabC, tabP, cfused, pfused,
        comp_idx, prot_idx, comp_lens, prot_lens, imp_c, imp_p_part);

    // ---- merged sigmoid gating (both tensors, ragged row skip) ----
    gate_both<<<dim3((NB * MC + NB * MP) / 64), 256, 0, stream>>>(cfused, Wcat, bias_cat,
        comp_lens, prot_lens);

    // ---- pooling + logit (bounded loops) ----
    pool_kernel<<<dim3(NB), 256, 0, stream>>>(cfused, pfused, imp_c, imp_p_part, comp_lens, prot_lens, out);
}